// Round 2
// baseline (435.433 us; speedup 1.0000x reference)
//
#include <hip/hip_runtime.h>

#define BB 8
#define IC 32
#define OC 64
#define HH 256
#define WW 256
#define EPS 1e-5f

typedef __attribute__((ext_vector_type(8))) short bf16x8;
typedef __attribute__((ext_vector_type(4))) float f32x4;

#define YSTR 40   // ys per-pixel stride in shorts (32 ch + 8 pad)
#define XSTR 40   // fallback xs per-pixel stride in shorts (32 ic + 8 pad)

// ---- workspace layout (float indices) ----
#define WS_GAP   0                      // 256 (zeroed by prep, accumulated by xform)
#define WS_BIDX  256                    // 8 ints
#define WS_W1F   264                    // 18432 bf16 = 9216 floats (conv1 A-frags)
#define WS_B1F   (WS_W1F + 9216)        // 64
#define WS_W2F   (WS_B1F + 64)          // 102400 bf16 = 51200 floats (conv2 A-frags)
#define WS_B2F   (WS_W2F + 51200)       // 64
#define WS_SXWT  (WS_B2F + 64)          // 51200 (fp32 [ic][k][oc], edge branch)
#define WS_SXBF  (WS_SXWT + 51200)      // 64
#define WS_SYWT  (WS_SXBF + 64)         // 51200
#define WS_SYBF  (WS_SYWT + 51200)      // 64
#define WS_LWT   (WS_SYBF + 64)         // 51200
#define WS_LBF   (WS_LWT + 51200)       // 64
// ---- fast-path extension (only touched when ws_size admits it) ----
#define WS_XT    (WS_LBF + 64)          // 8*65536 px * 32ch bf16 = 8388608 floats (NHWC x)
#define WS_ZPAD  (WS_XT + 8388608)      // 16 floats of zeros (OOB target for global_load_lds)
#define WS_NEED_FAST ((size_t)(WS_ZPAD + 16) * 4)

__device__ inline unsigned short bf16r(float f) {
    unsigned int u = __float_as_uint(f);
    unsigned int r = (u + 0x7fffu + ((u >> 16) & 1u)) >> 16;
    return (unsigned short)r;
}

// async 16B global->LDS (per-lane global src, wave-uniform LDS base + lane*16)
__device__ __forceinline__ void gld16(const void* g, const void* l) {
    __builtin_amdgcn_global_load_lds(
        (const __attribute__((address_space(1))) void*)(unsigned long long)(g),
        (__attribute__((address_space(3))) void*)(unsigned int)(unsigned long long)(l),
        16, 0, 0);
}

// ------------------------------------------------------------------
// prep: fold BN scales into weights. Zero gap accumulators; zero the
// zpad block only when the fast path owns that part of the workspace.
// ------------------------------------------------------------------
__global__ void prep_kernel(const float* __restrict__ mw1, const float* __restrict__ mb1, const float* __restrict__ mbn1,
                            const float* __restrict__ mw2, const float* __restrict__ mb2, const float* __restrict__ mbn2,
                            const float* __restrict__ sxw, const float* __restrict__ sxb, const float* __restrict__ sxbn,
                            const float* __restrict__ syw, const float* __restrict__ syb, const float* __restrict__ sybn,
                            const float* __restrict__ lw,  const float* __restrict__ lb,  const float* __restrict__ lbn,
                            float* __restrict__ ws, int fast) {
    int idx = blockIdx.x * 256 + threadIdx.x;

    if (idx < 18432) {  // conv1 A-frags
        int j = idx & 7, lane = (idx >> 3) & 63, oct = (idx >> 9) & 1, ht = idx >> 10;
        int t = ht % 9, h = ht / 9;
        int oc = h * 32 + oct * 16 + (lane & 15);
        int ic = (lane >> 4) * 8 + j;
        float s = mbn1[oc] * rsqrtf(mbn1[192 + oc] + EPS);
        ((unsigned short*)(ws + WS_W1F))[idx] = bf16r(mw1[(oc * IC + ic) * 9 + t] * s);
    }
    if (idx < 102400) {  // conv2 A-frags
        int j = idx & 7, lane = (idx >> 3) & 63, oct = (idx >> 9) & 3, ht = idx >> 11;
        int t = ht % 25, h = ht / 25;
        int oc = oct * 16 + (lane & 15);
        int ic = h * 32 + (lane >> 4) * 8 + j;
        float s = mbn2[oc] * rsqrtf(mbn2[192 + oc] + EPS);
        ((unsigned short*)(ws + WS_W2F))[idx] = bf16r(mw2[(oc * OC + ic) * 25 + t] * s);
    }
    if (idx < 51200) {  // edge-branch fp32 transposed weights [ic][k][oc]
        int oc = idx & 63, k = (idx >> 6) % 25, ic = idx / (25 * 64);
        float ssx = sxbn[oc] * rsqrtf(sxbn[192 + oc] + EPS);
        float ssy = sybn[oc] * rsqrtf(sybn[192 + oc] + EPS);
        float sl  = lbn[oc]  * rsqrtf(lbn[192 + oc]  + EPS);
        ws[WS_SXWT + idx] = sxw[(oc * IC + ic) * 25 + k] * ssx;
        ws[WS_SYWT + idx] = syw[(oc * IC + ic) * 25 + k] * ssy;
        ws[WS_LWT  + idx] = lw [(oc * IC + ic) * 25 + k] * sl;
    }
    if (idx < 256) ws[WS_GAP + idx] = 0.f;
    if (fast && idx < 16) ws[WS_ZPAD + idx] = 0.f;
    if (idx < 64) {
        float s1 = mbn1[idx] * rsqrtf(mbn1[192 + idx] + EPS);
        ws[WS_B1F + idx] = (mb1[idx] - mbn1[128 + idx]) * s1 + mbn1[64 + idx];
        float s2 = mbn2[idx] * rsqrtf(mbn2[192 + idx] + EPS);
        ws[WS_B2F + idx] = (mb2[idx] - mbn2[128 + idx]) * s2 + mbn2[64 + idx];
        float sx = sxbn[idx] * rsqrtf(sxbn[192 + idx] + EPS);
        ws[WS_SXBF + idx] = (sxb[idx] - sxbn[128 + idx]) * sx + sxbn[64 + idx];
        float sy = sybn[idx] * rsqrtf(sybn[192 + idx] + EPS);
        ws[WS_SYBF + idx] = (syb[idx] - sybn[128 + idx]) * sy + sybn[64 + idx];
        float sl = lbn[idx] * rsqrtf(lbn[192 + idx] + EPS);
        ws[WS_LBF + idx] = (lb[idx] - lbn[128 + idx]) * sl + lbn[64 + idx];
    }
}

// ------------------------------------------------------------------
// FAST path: NCHW fp32 -> NHWC bf16 (xt, 64B per pixel) + GAP sums.
// Block = one (batch,row). Phase A: thread t owns pixel t (32 coalesced
// ch loads, packed 64B store). Phase B: re-read the L1/L2-hot row for
// per-channel sums; atomicAdd into gap.
// ------------------------------------------------------------------
__global__ void __launch_bounds__(256, 2)
xform_kernel(const float* __restrict__ x, float* __restrict__ ws) {
    int b = blockIdx.y, row = blockIdx.x, t = threadIdx.x;
    const float* xb = x + (size_t)b * (IC * HH * WW) + (size_t)row * WW;

    unsigned int pk[16];
    #pragma unroll
    for (int k = 0; k < 32; k += 2) {
        float v0 = xb[(size_t)k * (HH * WW) + t];
        float v1 = xb[(size_t)(k + 1) * (HH * WW) + t];
        pk[k >> 1] = (unsigned int)bf16r(v0) | ((unsigned int)bf16r(v1) << 16);
    }
    short* xt = (short*)(ws + WS_XT) + ((size_t)b * (HH * WW) + (size_t)row * WW + t) * 32;
    uint4* dp = (uint4*)xt;
    dp[0] = make_uint4(pk[0],  pk[1],  pk[2],  pk[3]);
    dp[1] = make_uint4(pk[4],  pk[5],  pk[6],  pk[7]);
    dp[2] = make_uint4(pk[8],  pk[9],  pk[10], pk[11]);
    dp[3] = make_uint4(pk[12], pk[13], pk[14], pk[15]);

    __shared__ float gl[32];
    int w = t >> 6, lane = t & 63;
    #pragma unroll
    for (int kk = 0; kk < 8; kk++) {
        int k = w * 8 + kk;
        const float* rp = xb + (size_t)k * (HH * WW);
        float s = rp[lane] + rp[lane + 64] + rp[lane + 128] + rp[lane + 192];
        #pragma unroll
        for (int off = 32; off; off >>= 1) s += __shfl_down(s, off, 64);
        if (lane == 0) gl[k] = s;
    }
    __syncthreads();
    if (t < 32) atomicAdd(ws + WS_GAP + b * 32 + t, gl[t] * (1.f / (HH * WW)));
}

// FALLBACK path: standalone GAP (fast path folds this into xform)
__global__ void gap_kernel(const float* __restrict__ x, float* __restrict__ ws) {
    int bc = blockIdx.x;
    const float4* p = (const float4*)(x + (size_t)bc * (HH * WW));
    float s = 0.f;
    for (int i = threadIdx.x; i < (HH * WW) / 4; i += 256) {
        float4 v = p[i];
        s += (v.x + v.y) + (v.z + v.w);
    }
    #pragma unroll
    for (int off = 32; off; off >>= 1) s += __shfl_down(s, off, 64);
    __shared__ float red[4];
    int lane = threadIdx.x & 63, w = threadIdx.x >> 6;
    if (lane == 0) red[w] = s;
    __syncthreads();
    if (threadIdx.x == 0)
        ws[WS_GAP + bc] = (red[0] + red[1] + red[2] + red[3]) * (1.f / (HH * WW));
}

__global__ void gate_kernel(const float* __restrict__ w1, const float* __restrict__ b1,
                            const float* __restrict__ gbn,
                            const float* __restrict__ w2, const float* __restrict__ b2,
                            float* __restrict__ ws) {
    __shared__ float hsh[8][32];
    int tid = threadIdx.x;
    int b = tid >> 5, j = tid & 31;
    float acc = b1[j];
    for (int i = 0; i < 32; i++) acc += ws[WS_GAP + b * 32 + i] * w1[j * 32 + i];
    float s = gbn[j] * rsqrtf(gbn[96 + j] + EPS);
    hsh[b][j] = tanhf((acc - gbn[64 + j]) * s + gbn[32 + j]);
    __syncthreads();
    if (tid < 8) {
        float best = -1e30f; int bi = 0;
        for (int c = 0; c < 3; c++) {
            float k = b2[c];
            for (int jj = 0; jj < 32; jj++) k += hsh[tid][jj] * w2[c * 32 + jj];
            if (k > best) { best = k; bi = c; }
        }
        ((int*)ws)[WS_BIDX + tid] = bi;
    }
}

// ------------------------------------------------------------------
// main branch: fused conv3x3+bn+relu -> conv5x5+bn+relu via bf16 MFMA.
// ASYNC=1: xs staged async from NHWC bf16 xt via global_load_lds (16B,
//   per-lane src; OOB lanes read the zero-pad block). xs is linear
//   64B/pixel with XOR swizzle: byte bits[6:4] ^= bits[9:7], applied on
//   the global SOURCE address (write side) and on every ds_read address
//   (read side, rule 21) -> each 16-lane phase spreads 2/bank-group.
// ASYNC=0: R3-verified fp32 gather staging (ws_size too small for xt).
// conv2 weight A-frags prefetched 4 k-steps deep in named registers.
// LDS: xs (31744B async / 38720B fallback) + ys 32000B -> 2 blk/CU.
// ------------------------------------------------------------------
template <int ASYNC>
__global__ void __launch_bounds__(256, 2)
main_kernel(const float* __restrict__ x, const float* __restrict__ ws, float* __restrict__ out) {
    __shared__ __align__(1024) short xs[ASYNC ? 496 * 32 : 484 * XSTR];
    __shared__ __align__(16)   short ys[400 * YSTR];

    int b = blockIdx.y;
    if (((const int*)ws)[WS_BIDX + b] != 0) return;
    int tile = blockIdx.x;
    int ty = (tile >> 4) * 16, tx = (tile & 15) * 16;
    int tid = threadIdx.x;
    int w = tid >> 6, lane = tid & 63, n = lane & 15, quad = lane >> 4;

    // ---- stage x tile ----
    if constexpr (ASYNC) {
        const short* xtb = (const short*)(ws + WS_XT) + (size_t)b * (HH * WW * 32);
        const void* zp = (const void*)(ws + WS_ZPAD);
        for (int c = w; c < 31; c += 4) {
            int D = c * 1024 + (lane << 4);            // this lane's LDS dest byte
            int L = D ^ (((D >> 7) & 7) << 4);         // linear location it must hold
            int pL = L >> 6, qL = (L >> 4) & 3;
            int rr = pL / 22, cc2 = pL - rr * 22;
            int gy = ty - 3 + rr, gx = tx - 3 + cc2;
            bool v = (pL < 484) && ((unsigned)gy < HH) && ((unsigned)gx < WW);
            const void* src = v ? (const void*)(xtb + (((gy << 8) + gx) * 32) + (qL << 3)) : zp;
            gld16(src, (const void*)((const char*)xs + c * 1024));
        }
    } else {
        const float* xb = x + (size_t)b * IC * HH * WW;
        for (int p = tid; p < 484; p += 256) {
            int rr = p / 22, cc = p % 22;
            int gy = ty - 3 + rr, gx = tx - 3 + cc;
            bool v = ((unsigned)gy < HH) && ((unsigned)gx < WW);
            const float* xp = xb + gy * WW + gx;
            short* dst = xs + p * XSTR;
            #pragma unroll
            for (int ic = 0; ic < IC; ic += 4) {
                float f0 = v ? xp[(size_t)(ic + 0) * (HH * WW)] : 0.f;
                float f1 = v ? xp[(size_t)(ic + 1) * (HH * WW)] : 0.f;
                float f2 = v ? xp[(size_t)(ic + 2) * (HH * WW)] : 0.f;
                float f3 = v ? xp[(size_t)(ic + 3) * (HH * WW)] : 0.f;
                uint2 pk;
                pk.x = (unsigned int)bf16r(f0) | ((unsigned int)bf16r(f1) << 16);
                pk.y = (unsigned int)bf16r(f2) | ((unsigned int)bf16r(f3) << 16);
                *(uint2*)(dst + ic) = pk;
            }
        }
    }

    // B-frag loader: P = pixel index in the 22x22 halo tile
    auto ldb = [&](int P) -> bf16x8 {
        if constexpr (ASYNC) {
            int L = (P << 6) + (quad << 4);
            int A = L ^ (((L >> 7) & 7) << 4);
            return *(const bf16x8*)((const char*)xs + A);
        } else {
            return *(const bf16x8*)(xs + P * XSTR + quad * 8);
        }
    };

    const short* w1v = (const short*)(ws + WS_W1F);
    const bf16x8* w2v = (const bf16x8*)(ws + WS_W2F);

    f32x4 acc2[4][4];
    #pragma unroll
    for (int i = 0; i < 4; i++)
        #pragma unroll
        for (int jj = 0; jj < 4; jj++) acc2[i][jj] = (f32x4){0.f, 0.f, 0.f, 0.f};
    int mrow0 = w * 4;   // conv2 output rows of this wave
    int yr0   = w * 5;   // conv1 output rows of this wave

    __syncthreads();     // drains global_load_lds (vmcnt) + barrier

    #pragma unroll 1
    for (int h = 0; h < 2; h++) {
        if (h) __syncthreads();  // conv2 reads of prev half done before ys overwrite

        // ---- conv1 half h: Y[20x20][32] for conv1 oc = h*32 .. h*32+31 ----
        #pragma unroll
        for (int cg = 0; cg < 2; cg++) {
            int cb = cg * 4;
            f32x4 a1[5][2];
            #pragma unroll
            for (int rr = 0; rr < 5; rr++) {
                a1[rr][0] = (f32x4){0.f, 0.f, 0.f, 0.f};
                a1[rr][1] = (f32x4){0.f, 0.f, 0.f, 0.f};
            }
            #pragma unroll
            for (int dw = 0; dw < 3; dw++) {
                bf16x8 w1f[3][2];
                #pragma unroll
                for (int dh = 0; dh < 3; dh++) {
                    int t = dh * 3 + dw;
                    w1f[dh][0] = *(const bf16x8*)(w1v + (((h * 9 + t) * 2 + 0) * 64 + lane) * 8);
                    w1f[dh][1] = *(const bf16x8*)(w1v + (((h * 9 + t) * 2 + 1) * 64 + lane) * 8);
                }
                bf16x8 bfr[7];
                #pragma unroll
                for (int rI = 0; rI < 7; rI++)
                    bfr[rI] = ldb((yr0 + rI) * 22 + cb + n + dw);
                #pragma unroll
                for (int dh = 0; dh < 3; dh++)
                    #pragma unroll
                    for (int rr = 0; rr < 5; rr++) {
                        a1[rr][0] = __builtin_amdgcn_mfma_f32_16x16x32_bf16(w1f[dh][0], bfr[rr + dh], a1[rr][0], 0, 0, 0);
                        a1[rr][1] = __builtin_amdgcn_mfma_f32_16x16x32_bf16(w1f[dh][1], bfr[rr + dh], a1[rr][1], 0, 0, 0);
                    }
            }
            // epilogue: relu(a1 + bias1) -> bf16 -> ys
            #pragma unroll
            for (int oct = 0; oct < 2; oct++) {
                float bias1[4];
                #pragma unroll
                for (int r = 0; r < 4; r++)
                    bias1[r] = ws[WS_B1F + h * 32 + oct * 16 + quad * 4 + r];
                #pragma unroll
                for (int rr = 0; rr < 5; rr++) {
                    int yr = yr0 + rr;
                    int gy2 = ty - 2 + yr, gx2 = tx - 2 + cb + n;
                    bool inb = ((unsigned)gy2 < HH) && ((unsigned)gx2 < WW);
                    float v0 = inb ? fmaxf(a1[rr][oct][0] + bias1[0], 0.f) : 0.f;
                    float v1 = inb ? fmaxf(a1[rr][oct][1] + bias1[1], 0.f) : 0.f;
                    float v2 = inb ? fmaxf(a1[rr][oct][2] + bias1[2], 0.f) : 0.f;
                    float v3 = inb ? fmaxf(a1[rr][oct][3] + bias1[3], 0.f) : 0.f;
                    uint2 pkk;
                    pkk.x = (unsigned int)bf16r(v0) | ((unsigned int)bf16r(v1) << 16);
                    pkk.y = (unsigned int)bf16r(v2) | ((unsigned int)bf16r(v3) << 16);
                    *(uint2*)(ys + (yr * 20 + cb + n) * YSTR + oct * 16 + quad * 4) = pkk;
                }
            }
        }
        __syncthreads();

        // ---- conv2 partial: K-step = this half's 32 channels, 25 taps ----
        const bf16x8* w2h = w2v + (size_t)h * 100 * 64;
        bf16x8 afq[4][4];   // 4-deep k prefetch ring, [slot][oc-tile]
        #pragma unroll
        for (int kp = 0; kp < 4; kp++) {
            int tn = (kp % 5) * 5 + (kp / 5);
            int base = tn * 256 + lane;
            afq[kp][0] = w2h[base];       afq[kp][1] = w2h[base + 64];
            afq[kp][2] = w2h[base + 128]; afq[kp][3] = w2h[base + 192];
        }
        bf16x8 bfr2[8];
        #pragma unroll
        for (int k = 0; k < 25; k++) {
            int dw = k / 5, dh = k % 5;
            if (dh == 0) {
                #pragma unroll
                for (int rI = 0; rI < 8; rI++)
                    bfr2[rI] = *(const bf16x8*)(ys + ((mrow0 + rI) * 20 + n + dw) * YSTR + quad * 8);
            }
            #pragma unroll
            for (int r4 = 0; r4 < 4; r4++) {
                bf16x8 bb = bfr2[r4 + dh];
                acc2[r4][0] = __builtin_amdgcn_mfma_f32_16x16x32_bf16(afq[k & 3][0], bb, acc2[r4][0], 0, 0, 0);
                acc2[r4][1] = __builtin_amdgcn_mfma_f32_16x16x32_bf16(afq[k & 3][1], bb, acc2[r4][1], 0, 0, 0);
                acc2[r4][2] = __builtin_amdgcn_mfma_f32_16x16x32_bf16(afq[k & 3][2], bb, acc2[r4][2], 0, 0, 0);
                acc2[r4][3] = __builtin_amdgcn_mfma_f32_16x16x32_bf16(afq[k & 3][3], bb, acc2[r4][3], 0, 0, 0);
            }
            if (k + 4 < 25) {
                int kk = k + 4;
                int tn = (kk % 5) * 5 + (kk / 5);
                int base = tn * 256 + lane;
                afq[k & 3][0] = w2h[base];       afq[k & 3][1] = w2h[base + 64];
                afq[k & 3][2] = w2h[base + 128]; afq[k & 3][3] = w2h[base + 192];
            }
        }
    }

    // ---- epilogue: relu(acc + b2f), store ----
    float bias2[4][4];
    #pragma unroll
    for (int oct = 0; oct < 4; oct++)
        #pragma unroll
        for (int r = 0; r < 4; r++)
            bias2[oct][r] = ws[WS_B2F + oct * 16 + quad * 4 + r];

    float* ob = out + (size_t)b * OC * HH * WW;
    #pragma unroll
    for (int r4 = 0; r4 < 4; r4++) {
        int orow = mrow0 + r4;
        #pragma unroll
        for (int oct = 0; oct < 4; oct++) {
            #pragma unroll
            for (int r = 0; r < 4; r++) {
                int oc = oct * 16 + quad * 4 + r;
                float v = fmaxf(acc2[r4][oct][r] + bias2[oct][r], 0.f);
                ob[(size_t)oc * (HH * WW) + (ty + orow) * WW + tx + n] = v;
            }
        }
    }
}

// ------------------------------------------------------------------
// edge branches merged into ONE kernel (fp32; early-exit when batch
// selects main). sel==1 (sobel): SX pass writes, SY pass accumulates —
// sequential within the block, so no inter-kernel ordering needed.
// sel==2 (lap): single pass.
// ------------------------------------------------------------------
__global__ void __launch_bounds__(256, 2)
edge_kernel(const float* __restrict__ x, const float* __restrict__ ws, float* __restrict__ out) {
    constexpr float KSX[9] = {1, 0, -1, 2, 0, -2, 1, 0, -1};
    constexpr float KSY[9] = {1, 2, 1, 0, 0, 0, -1, -2, -1};
    constexpr float KLP[9] = {0, 1, 0, 1, -4, 1, 0, 1, 0};

    __shared__ float xsf[8 * 484];
    __shared__ float ysf[8 * 400];
    int b = blockIdx.y;
    int sel = ((const int*)ws)[WS_BIDX + b];
    if (sel == 0) return;
    int npass = (sel == 1) ? 2 : 1;
    float scale = (sel == 1) ? 0.5f : 1.0f;

    int tile = blockIdx.x;
    int ty = (tile >> 4) * 16, tx = (tile & 15) * 16;
    int tid = threadIdx.x;
    const float* xb = x + (size_t)b * IC * HH * WW;

    int ocg = tid >> 5;
    int ps  = tid & 31;
    int row = ps >> 1, c0 = (ps & 1) * 8;

    for (int pass = 0; pass < npass; pass++) {
        int kid = (sel == 1) ? pass : 2;
        const float* wt = ws + (kid == 0 ? WS_SXWT : (kid == 1 ? WS_SYWT : WS_LWT));
        const float* bf = ws + (kid == 0 ? WS_SXBF : (kid == 1 ? WS_SYBF : WS_LBF));

        float acc[8][8];
        #pragma unroll
        for (int o = 0; o < 8; o++)
            #pragma unroll
            for (int j = 0; j < 8; j++) acc[o][j] = 0.f;

        for (int icc = 0; icc < 4; icc++) {
            if (icc || pass) __syncthreads();
            for (int i = tid; i < 8 * 484; i += 256) {
                int ch = i / 484, rem = i % 484, rr = rem / 22, cc = rem % 22;
                int ic = icc * 8 + ch;
                int gy = ty - 3 + rr, gx = tx - 3 + cc;
                float v = 0.f;
                if ((unsigned)gy < HH && (unsigned)gx < WW) v = xb[(size_t)ic * HH * WW + gy * WW + gx];
                xsf[i] = v;
            }
            __syncthreads();
            for (int p = tid; p < 400; p += 256) {
                int r = p / 20, c = p % 20;
                bool inb = ((unsigned)(ty - 2 + r) < HH) && ((unsigned)(tx - 2 + c) < WW);
                #pragma unroll
                for (int ch = 0; ch < 8; ch++) {
                    const float* xp = xsf + ch * 484 + r * 22 + c;
                    float v = 0.f;
                    #pragma unroll
                    for (int k = 0; k < 9; k++) {
                        float kv = (kid == 0) ? KSX[k] : (kid == 1) ? KSY[k] : KLP[k];
                        v += kv * xp[(k / 3) * 22 + (k % 3)];
                    }
                    ysf[ch * 400 + p] = inb ? v : 0.f;
                }
            }
            __syncthreads();
            for (int ic8 = 0; ic8 < 8; ic8++) {
                const float* yc = ysf + ic8 * 400;
                const float* wbase = wt + ((icc * 8 + ic8) * 25) * 64 + ocg * 8;
                #pragma unroll
                for (int dh = 0; dh < 5; dh++) {
                    #pragma unroll
                    for (int dw = 0; dw < 5; dw++) {
                        const float* yp = yc + (row + dh) * 20 + c0 + dw;
                        float yv[8];
                        #pragma unroll
                        for (int j = 0; j < 8; j++) yv[j] = yp[j];
                        const float4* wp = (const float4*)(wbase + (dh * 5 + dw) * 64);
                        float4 wa = wp[0], wb = wp[1];
                        float wr[8] = {wa.x, wa.y, wa.z, wa.w, wb.x, wb.y, wb.z, wb.w};
                        #pragma unroll
                        for (int o = 0; o < 8; o++)
                            #pragma unroll
                            for (int j = 0; j < 8; j++) acc[o][j] += wr[o] * yv[j];
                    }
                }
            }
        }
        float* ob = out + (size_t)b * OC * HH * WW;
        #pragma unroll
        for (int o = 0; o < 8; o++) {
            int oc = ocg * 8 + o;
            float bb = bf[oc];
            float* op = ob + (size_t)oc * HH * WW + (ty + row) * WW + tx + c0;
            if (pass) {
                #pragma unroll
                for (int j = 0; j < 8; j++) op[j] += scale * fmaxf(acc[o][j] + bb, 0.f);
            } else {
                #pragma unroll
                for (int j = 0; j < 8; j++) op[j] = scale * fmaxf(acc[o][j] + bb, 0.f);
            }
        }
    }
}

// ------------------------------------------------------------------
extern "C" void kernel_launch(void* const* d_in, const int* in_sizes, int n_in,
                              void* d_out, int out_size, void* d_ws, size_t ws_size,
                              hipStream_t stream) {
    const float* x    = (const float*)d_in[0];
    const float* gw1  = (const float*)d_in[1];
    const float* gb1  = (const float*)d_in[2];
    const float* gbn  = (const float*)d_in[3];
    const float* gw2  = (const float*)d_in[4];
    const float* gb2  = (const float*)d_in[5];
    const float* mw1  = (const float*)d_in[6];
    const float* mb1  = (const float*)d_in[7];
    const float* mbn1 = (const float*)d_in[8];
    const float* mw2  = (const float*)d_in[9];
    const float* mb2  = (const float*)d_in[10];
    const float* mbn2 = (const float*)d_in[11];
    const float* sxw  = (const float*)d_in[12];
    const float* sxb  = (const float*)d_in[13];
    const float* sxbn = (const float*)d_in[14];
    const float* syw  = (const float*)d_in[15];
    const float* syb  = (const float*)d_in[16];
    const float* sybn = (const float*)d_in[17];
    const float* lw   = (const float*)d_in[18];
    const float* lb   = (const float*)d_in[19];
    const float* lbn  = (const float*)d_in[20];
    float* ws  = (float*)d_ws;
    float* out = (float*)d_out;

    // Fast path needs the 34.4 MB xt extension; fall back if the harness
    // workspace is smaller (constant per-process -> graph-capture safe).
    int fast = (ws_size >= WS_NEED_FAST) ? 1 : 0;

    prep_kernel<<<400, 256, 0, stream>>>(mw1, mb1, mbn1, mw2, mb2, mbn2,
                                         sxw, sxb, sxbn, syw, syb, sybn, lw, lb, lbn, ws, fast);
    if (fast) {
        xform_kernel<<<dim3(HH, BB), 256, 0, stream>>>(x, ws);
    } else {
        gap_kernel<<<256, 256, 0, stream>>>(x, ws);
    }
    gate_kernel<<<1, 256, 0, stream>>>(gw1, gb1, gbn, gw2, gb2, ws);

    dim3 grid(256, BB);
    if (fast) {
        main_kernel<1><<<grid, 256, 0, stream>>>(x, ws, out);
    } else {
        main_kernel<0><<<grid, 256, 0, stream>>>(x, ws, out);
    }
    edge_kernel<<<grid, 256, 0, stream>>>(x, ws, out);
}